// Round 3
// baseline (296.078 us; speedup 1.0000x reference)
//
#include <hip/hip_runtime.h>
#include <math.h>

// Problem constants (from reference)
#define BB 16
#define VV 6890
#define NFF 13776
#define HH 512
#define WW 512
// SIGMA = 1e-4 -> 1/SIGMA = 1e4

typedef float nf4 __attribute__((ext_vector_type(4)));

// ---------------------------------------------------------------------------
// Kernel 1 (k_mesh): ENTIRE mesh preprocessing in one kernel, one block per
// batch. The per-batch vertex-normal accumulator (3 x 6890 floats = 82.7 KB)
// fits in LDS, so:
//   phase A: each thread computes face normals and scatter-adds into LDS
//            (ds_add_f32 atomics -- ~124K per block spread over 16 waves of
//            one CU, vs round-2's fatal 41K-atomic single-CSR-block tail)
//   phase B: normalize vn in LDS
//   phase C: fas[b,f] = vn[f0]+vn[f1]+vn[f2], gathered from LDS, written out
// Replaces fn/count/scan/fill/vn/face_sum + two 3.5MB global round-trips.
// 16 blocks (2 per XCD), 1024 threads, LDS-limited to 1 block/CU -- fine.
// ---------------------------------------------------------------------------
#define MESH_T 1024

__global__ __launch_bounds__(MESH_T) void k_mesh(const float* __restrict__ verts,
                                                 const int* __restrict__ faces,
                                                 float4* __restrict__ fas4) {
    __shared__ float vx[VV];
    __shared__ float vy[VV];
    __shared__ float vz[VV];
    int b = blockIdx.x;
    int t = threadIdx.x;

    for (int v = t; v < VV; v += MESH_T) { vx[v] = 0.f; vy[v] = 0.f; vz[v] = 0.f; }
    __syncthreads();

    const float* vb = verts + (size_t)b * (VV * 3);
    for (int f = t; f < NFF; f += MESH_T) {
        int i0 = faces[3 * f + 0];
        int i1 = faces[3 * f + 1];
        int i2 = faces[3 * f + 2];
        float ax = vb[3 * i0 + 0], ay = vb[3 * i0 + 1], az = vb[3 * i0 + 2];
        float bx = vb[3 * i1 + 0], by = vb[3 * i1 + 1], bz = vb[3 * i1 + 2];
        float cx = vb[3 * i2 + 0], cy = vb[3 * i2 + 1], cz = vb[3 * i2 + 2];
        float e1x = bx - ax, e1y = by - ay, e1z = bz - az;
        float e2x = cx - ax, e2y = cy - ay, e2z = cz - az;
        float nx = e1y * e2z - e1z * e2y;
        float ny = e1z * e2x - e1x * e2z;
        float nz = e1x * e2y - e1y * e2x;
        atomicAdd(&vx[i0], nx); atomicAdd(&vy[i0], ny); atomicAdd(&vz[i0], nz);
        atomicAdd(&vx[i1], nx); atomicAdd(&vy[i1], ny); atomicAdd(&vz[i1], nz);
        atomicAdd(&vx[i2], nx); atomicAdd(&vy[i2], ny); atomicAdd(&vz[i2], nz);
    }
    __syncthreads();

    for (int v = t; v < VV; v += MESH_T) {
        float x = vx[v], y = vy[v], z = vz[v];
        float inv = 1.0f / fmaxf(sqrtf(x * x + y * y + z * z), 1e-6f);
        vx[v] = x * inv; vy[v] = y * inv; vz[v] = z * inv;
    }
    __syncthreads();

    float4* fasb = fas4 + (size_t)b * NFF;
    for (int f = t; f < NFF; f += MESH_T) {
        int i0 = faces[3 * f + 0];
        int i1 = faces[3 * f + 1];
        int i2 = faces[3 * f + 2];
        float4 o;
        o.x = vx[i0] + vx[i1] + vx[i2];
        o.y = vy[i0] + vy[i1] + vy[i2];
        o.z = vz[i0] + vz[i1] + vz[i2];
        o.w = 0.f;
        fasb[f] = o;
    }
}

// ---------------------------------------------------------------------------
// Kernel 2 (k_pixel): per-pixel gather + normalize + alpha.
// 8 pixels/thread with a STRIDED mapping: thread t owns pixels
// base + k*256 + t. Every p2f/dists load and every output store instruction
// is 64 consecutive lanes x contiguous addresses -> fully coalesced (fixes
// round-2's 179MB WRITE_SIZE from 128B-strided partial-line stores), while
// the 8 independent clamped gathers still issue back-to-back for MLP.
// ---------------------------------------------------------------------------
__device__ __forceinline__ nf4 pixel_one(int f, float d, float4 p) {
    float m = (f >= 0) ? 1.0f : 0.0f;
    float px = p.x * m, py = p.y * m, pz = p.z * m;
    float prob = m / (1.0f + __expf(d * 1.0e4f));  // sigmoid(-d/SIGMA) * mask
    float n2 = px * px + py * py + pz * pz;
    float inv = 1.0f / fmaxf(sqrtf(n2), 1e-12f);
    float hitadd = (n2 > 0.f) ? 0.f : 1.0f;
    nf4 o;
    o.x = px * inv + hitadd;
    o.y = py * inv + hitadd;
    o.z = pz * inv + hitadd;
    o.w = 1.0f - prob;
    return o;
}

#define PPT 8
#define PIX_BLOCK (256 * PPT)  // 2048 pixels per block; 128 blocks per batch

__global__ __launch_bounds__(256) void k_pixel(const int* __restrict__ p2f,
                                               const float* __restrict__ dists,
                                               const float4* __restrict__ fas4,
                                               nf4* __restrict__ out) {
    int base = blockIdx.x * PIX_BLOCK;
    int t = threadIdx.x;
    int b = base >> 18;  // H*W = 2^18; a 2048-pixel block never crosses a batch
    const float4* fasb = fas4 + (size_t)b * NFF;

    int   f[PPT];
    float d[PPT];
    float4 p[PPT];

    // Streamed inputs: coalesced scalar loads (256 B / wave / instruction),
    // nontemporal so they don't evict the fas4 slab from L2.
#pragma unroll
    for (int k = 0; k < PPT; k++)
        f[k] = __builtin_nontemporal_load(p2f + base + k * 256 + t);
#pragma unroll
    for (int k = 0; k < PPT; k++)
        d[k] = __builtin_nontemporal_load(dists + base + k * 256 + t);

    // 8 unconditional clamped gathers, all in flight before first use.
#pragma unroll
    for (int k = 0; k < PPT; k++)
        p[k] = fasb[min(max(f[k], 0), NFF - 1)];

#pragma unroll
    for (int k = 0; k < PPT; k++) {
        nf4 o = pixel_one(f[k], d[k], p[k]);
        __builtin_nontemporal_store(o, out + base + k * 256 + t);  // 1024 B/wave/instr
    }
}

// ---------------------------------------------------------------------------
extern "C" void kernel_launch(void* const* d_in, const int* in_sizes, int n_in,
                              void* d_out, int out_size, void* d_ws, size_t ws_size,
                              hipStream_t stream) {
    const float* verts = (const float*)d_in[0];
    // d_in[1] = zbuf: dead in the reference's returned value -> never read
    const float* dists = (const float*)d_in[2];
    const int* faces   = (const int*)d_in[3];
    const int* p2f     = (const int*)d_in[4];

    float4* fas4 = (float4*)d_ws;  // 3.53 MB, the only intermediate buffer

    k_mesh<<<BB, MESH_T, 0, stream>>>(verts, faces, fas4);
    k_pixel<<<BB * HH * WW / PIX_BLOCK, 256, 0, stream>>>(p2f, dists, fas4, (nf4*)d_out);
}

// Round 4
// 159.687 us; speedup vs baseline: 1.8541x; 1.8541x over previous
//
#include <hip/hip_runtime.h>
#include <math.h>

// Problem constants (from reference)
#define BB 16
#define VV 6890
#define NFF 13776
#define HH 512
#define WW 512
#define CAP 32            // vertex-degree bucket capacity; deg ~ Poisson(6), P(>=32) ~ 1e-15
// SIGMA = 1e-4 -> 1/SIGMA = 1e4

typedef float nf4 __attribute__((ext_vector_type(4)));

// ---------------------------------------------------------------------------
// Dispatch 2 (k_fn_adj): fully distributed, no single-block tail.
//   blocks [0, 861):   per-(batch,face) normals -> fn4   (861*256 == BB*NFF exact)
//   blocks [861, 915): vertex->face bucket fill, 54 blocks cover NFF faces.
//     slot = atomicAdd(cursor[v]) -- 41K int atomics over 6890 L2-resident
//     counters (round-0's k_count proved this cheap). adj is SLOT-MAJOR
//     (adj[slot*VV+v]) so k_vn's lane-consecutive vertices read coalesced.
// ---------------------------------------------------------------------------
__global__ __launch_bounds__(256) void k_fn_adj(const float* __restrict__ verts,
                                                const int* __restrict__ faces,
                                                float4* __restrict__ fn4,
                                                int* __restrict__ cursor,
                                                int* __restrict__ adj) {
    if (blockIdx.x < 861) {
        int i = blockIdx.x * 256 + threadIdx.x;   // < 220416 exactly
        int b = i / NFF;
        int f = i - b * NFF;
        int i0 = faces[3 * f + 0];
        int i1 = faces[3 * f + 1];
        int i2 = faces[3 * f + 2];
        const float* vb = verts + (size_t)b * (VV * 3);
        float ax = vb[3 * i0 + 0], ay = vb[3 * i0 + 1], az = vb[3 * i0 + 2];
        float bx = vb[3 * i1 + 0], by = vb[3 * i1 + 1], bz = vb[3 * i1 + 2];
        float cx = vb[3 * i2 + 0], cy = vb[3 * i2 + 1], cz = vb[3 * i2 + 2];
        float e1x = bx - ax, e1y = by - ay, e1z = bz - az;
        float e2x = cx - ax, e2y = cy - ay, e2z = cz - az;
        float4 n;
        n.x = e1y * e2z - e1z * e2y;
        n.y = e1z * e2x - e1x * e2z;
        n.z = e1x * e2y - e1y * e2x;
        n.w = 0.f;
        fn4[i] = n;
    } else {
        int f = (blockIdx.x - 861) * 256 + threadIdx.x;
        if (f < NFF) {
            int i0 = faces[3 * f + 0];
            int i1 = faces[3 * f + 1];
            int i2 = faces[3 * f + 2];
            int s0 = atomicAdd(&cursor[i0], 1);
            adj[s0 * VV + i0] = f;
            int s1 = atomicAdd(&cursor[i1], 1);
            adj[s1 * VV + i1] = f;
            int s2 = atomicAdd(&cursor[i2], 1);
            adj[s2 * VV + i2] = f;
        }
    }
}

// ---------------------------------------------------------------------------
// Dispatch 3 (k_vn): per-(batch,vertex) gather adjacent face normals, normalize.
// cursor[v] doubles as the degree. adj reads coalesce (slot-major layout).
// ---------------------------------------------------------------------------
__global__ __launch_bounds__(256) void k_vn(const float4* __restrict__ fn4,
                                            const int* __restrict__ cursor,
                                            const int* __restrict__ adj,
                                            float4* __restrict__ vn4) {
    int i = blockIdx.x * 256 + threadIdx.x;
    if (i >= BB * VV) return;
    int b = i / VV;
    int v = i - b * VV;
    int deg = cursor[v];
    float x = 0.f, y = 0.f, z = 0.f;
    const float4* fnb = fn4 + (size_t)b * NFF;
    for (int j = 0; j < deg; j++) {
        float4 n = fnb[adj[j * VV + v]];
        x += n.x; y += n.y; z += n.z;
    }
    float inv = 1.0f / fmaxf(sqrtf(x * x + y * y + z * z), 1e-6f);
    float4 o; o.x = x * inv; o.y = y * inv; o.z = z * inv; o.w = 0.f;
    vn4[i] = o;
}

// ---------------------------------------------------------------------------
// Dispatch 4 (k_fas): fas[b,f] = vn[f0] + vn[f1] + vn[f2]  (proven round-0 code)
// ---------------------------------------------------------------------------
__global__ __launch_bounds__(256) void k_fas(const float4* __restrict__ vn4,
                                             const int* __restrict__ faces,
                                             float4* __restrict__ fas4) {
    int i = blockIdx.x * 256 + threadIdx.x;   // exact: 861*256 == BB*NFF
    int b = i / NFF;
    int f = i - b * NFF;
    int i0 = faces[3 * f + 0], i1 = faces[3 * f + 1], i2 = faces[3 * f + 2];
    const float4* vnb = vn4 + (size_t)b * VV;
    float4 a = vnb[i0], bb = vnb[i1], cc = vnb[i2];
    float4 o;
    o.x = a.x + bb.x + cc.x;
    o.y = a.y + bb.y + cc.y;
    o.z = a.z + bb.z + cc.z;
    o.w = 0.f;
    fas4[i] = o;
}

// ---------------------------------------------------------------------------
// Dispatch 5 (k_pixel): per-pixel gather + normalize + alpha.
// STRIDED 8 px/thread: thread t owns pixels base + k*256 + t, so every input
// load (256 B/wave) and output store (1 KB/wave) is contiguous -- round-2's
// blocked layout proved 128B-strided 16B stores cost 2.7x write amplification.
// 8 independent clamped gathers in flight per thread attack the gather
// latency that held round-0 at 2.2 TB/s.
// ---------------------------------------------------------------------------
__device__ __forceinline__ nf4 pixel_one(int f, float d, float4 p) {
    float m = (f >= 0) ? 1.0f : 0.0f;
    float px = p.x * m, py = p.y * m, pz = p.z * m;
    float prob = m / (1.0f + __expf(d * 1.0e4f));  // sigmoid(-d/SIGMA) * mask
    float n2 = px * px + py * py + pz * pz;
    float inv = 1.0f / fmaxf(sqrtf(n2), 1e-12f);
    float hitadd = (n2 > 0.f) ? 0.f : 1.0f;
    nf4 o;
    o.x = px * inv + hitadd;
    o.y = py * inv + hitadd;
    o.z = pz * inv + hitadd;
    o.w = 1.0f - prob;
    return o;
}

#define PPT 8
#define PIX_BLOCK (256 * PPT)  // 2048 pixels/block; 2048 blocks; 128 blocks/batch

__global__ __launch_bounds__(256) void k_pixel(const int* __restrict__ p2f,
                                               const float* __restrict__ dists,
                                               const float4* __restrict__ fas4,
                                               nf4* __restrict__ out) {
    int base = blockIdx.x * PIX_BLOCK;
    int t = threadIdx.x;
    int b = base >> 18;  // H*W = 2^18; a 2048-pixel block never crosses a batch
    const float4* fasb = fas4 + (size_t)b * NFF;

    int   f[PPT];
    float d[PPT];
    float4 p[PPT];

#pragma unroll
    for (int k = 0; k < PPT; k++)
        f[k] = __builtin_nontemporal_load(p2f + base + k * 256 + t);
#pragma unroll
    for (int k = 0; k < PPT; k++)
        d[k] = __builtin_nontemporal_load(dists + base + k * 256 + t);

    // 8 unconditional clamped gathers, all issued before first use (MLP).
#pragma unroll
    for (int k = 0; k < PPT; k++)
        p[k] = fasb[min(max(f[k], 0), NFF - 1)];

#pragma unroll
    for (int k = 0; k < PPT; k++) {
        nf4 o = pixel_one(f[k], d[k], p[k]);
        __builtin_nontemporal_store(o, out + base + k * 256 + t);
    }
}

// ---------------------------------------------------------------------------
extern "C" void kernel_launch(void* const* d_in, const int* in_sizes, int n_in,
                              void* d_out, int out_size, void* d_ws, size_t ws_size,
                              hipStream_t stream) {
    const float* verts = (const float*)d_in[0];
    // d_in[1] = zbuf: dead in the reference's returned value -> never read
    const float* dists = (const float*)d_in[2];
    const int* faces   = (const int*)d_in[3];
    const int* p2f     = (const int*)d_in[4];

    // Workspace layout (16B-aligned chunks)
    char* w = (char*)d_ws;
    float4* fn4  = (float4*)w;  w += (size_t)BB * NFF * 16;   // 3.53 MB
    float4* vn4  = (float4*)w;  w += (size_t)BB * VV * 16;    // 1.76 MB
    float4* fas4 = (float4*)w;  w += (size_t)BB * NFF * 16;   // 3.53 MB
    int* cursor  = (int*)w;     w += (VV * 4 + 15) / 16 * 16; // 27.6 KB
    int* adj     = (int*)w;                                   // CAP*VV*4 = 882 KB

    (void)hipMemsetAsync(cursor, 0, VV * sizeof(int), stream);

    int nbv = BB * VV;   // 110240
    k_fn_adj<<<861 + (NFF + 255) / 256, 256, 0, stream>>>(verts, faces, fn4, cursor, adj);
    k_vn<<<(nbv + 255) / 256, 256, 0, stream>>>(fn4, cursor, adj, vn4);
    k_fas<<<861, 256, 0, stream>>>(vn4, faces, fas4);
    k_pixel<<<BB * HH * WW / PIX_BLOCK, 256, 0, stream>>>(p2f, dists, fas4, (nf4*)d_out);
}

// Round 6
// 157.430 us; speedup vs baseline: 1.8807x; 1.0143x over previous
//
#include <hip/hip_runtime.h>
#include <math.h>

// Problem constants (from reference)
#define BB 16
#define VV 6890
#define NFF 13776
#define HH 512
#define WW 512
#define CAP 32            // fallback path: vertex-degree bucket capacity
// SIGMA = 1e-4 -> 1/SIGMA = 1e4

#define NS 16             // face-slices per batch; grid = BB*NS = 256 blocks (1/CU)
#define FPS ((NFF + NS - 1) / NS)   // 861 faces per slice (exact: 861*16 = 13776)

typedef float nf4 __attribute__((ext_vector_type(4)));

// ---------------------------------------------------------------------------
// D1 (k_scatter): block (b,s) computes face normals for its 861-face slice
// INLINE (fn4 buffer + dispatch eliminated: vn is fn's only consumer) and
// scatter-adds into a private 82.7KB LDS accumulator. 256 blocks saturate all
// CUs (vs round-3's 16-block starvation); only ~7.7K LDS atomics per block.
// Partial written out fully coalesced.
// ---------------------------------------------------------------------------
__global__ __launch_bounds__(512) void k_scatter(const float* __restrict__ verts,
                                                 const int* __restrict__ faces,
                                                 float* __restrict__ partial) {
    __shared__ float vx[VV];
    __shared__ float vy[VV];
    __shared__ float vz[VV];
    const int b = blockIdx.x / NS;
    const int s = blockIdx.x - b * NS;
    const int t = threadIdx.x;

    for (int v = t; v < VV; v += 512) { vx[v] = 0.f; vy[v] = 0.f; vz[v] = 0.f; }
    __syncthreads();

    const float* vb = verts + (size_t)b * (VV * 3);
    const int fend = min((s + 1) * FPS, NFF);
    for (int f = s * FPS + t; f < fend; f += 512) {
        int i0 = faces[3 * f + 0];
        int i1 = faces[3 * f + 1];
        int i2 = faces[3 * f + 2];
        float ax = vb[3 * i0 + 0], ay = vb[3 * i0 + 1], az = vb[3 * i0 + 2];
        float bx = vb[3 * i1 + 0], by = vb[3 * i1 + 1], bz = vb[3 * i1 + 2];
        float cx = vb[3 * i2 + 0], cy = vb[3 * i2 + 1], cz = vb[3 * i2 + 2];
        float e1x = bx - ax, e1y = by - ay, e1z = bz - az;
        float e2x = cx - ax, e2y = cy - ay, e2z = cz - az;
        float nx = e1y * e2z - e1z * e2y;
        float ny = e1z * e2x - e1x * e2z;
        float nz = e1x * e2y - e1y * e2x;
        atomicAdd(&vx[i0], nx); atomicAdd(&vy[i0], ny); atomicAdd(&vz[i0], nz);
        atomicAdd(&vx[i1], nx); atomicAdd(&vy[i1], ny); atomicAdd(&vz[i1], nz);
        atomicAdd(&vx[i2], nx); atomicAdd(&vy[i2], ny); atomicAdd(&vz[i2], nz);
    }
    __syncthreads();

    float* pb = partial + (size_t)blockIdx.x * (3 * VV);
    for (int v = t; v < VV; v += 512) pb[v] = vx[v];
    for (int v = t; v < VV; v += 512) pb[VV + v] = vy[v];
    for (int v = t; v < VV; v += 512) pb[2 * VV + v] = vz[v];
}

// ---------------------------------------------------------------------------
// D2 (k_vred): vn[b,v] = normalize( sum over NS slice-partials ). 48 fully
// coalesced INDEPENDENT loads per thread -- replaces round-4's dependent
// scattered-gather CSR loop (deg x ~300cy serialized L2 hits).
// ---------------------------------------------------------------------------
__global__ __launch_bounds__(256) void k_vred(const float* __restrict__ partial,
                                              float4* __restrict__ vn4) {
    int i = blockIdx.x * 256 + threadIdx.x;
    if (i >= BB * VV) return;
    int b = i / VV;
    int v = i - b * VV;
    float x = 0.f, y = 0.f, z = 0.f;
    const float* pb = partial + (size_t)b * NS * (3 * VV);
#pragma unroll
    for (int s = 0; s < NS; s++) {
        const float* ps = pb + (size_t)s * (3 * VV);
        x += ps[v];
        y += ps[VV + v];
        z += ps[2 * VV + v];
    }
    float inv = 1.0f / fmaxf(sqrtf(x * x + y * y + z * z), 1e-6f);
    float4 o; o.x = x * inv; o.y = y * inv; o.z = z * inv; o.w = 0.f;
    vn4[i] = o;
}

// ---------------------------------------------------------------------------
// D3 (k_fas): fas[b,f] = vn[i0] + vn[i1] + vn[i2]   (proven round-0/4 code)
// ---------------------------------------------------------------------------
__global__ __launch_bounds__(256) void k_fas(const float4* __restrict__ vn4,
                                             const int* __restrict__ faces,
                                             float4* __restrict__ fas4) {
    int i = blockIdx.x * 256 + threadIdx.x;   // exact: 861*256 == BB*NFF
    int b = i / NFF;
    int f = i - b * NFF;
    int i0 = faces[3 * f + 0], i1 = faces[3 * f + 1], i2 = faces[3 * f + 2];
    const float4* vnb = vn4 + (size_t)b * VV;
    float4 a = vnb[i0], bb = vnb[i1], cc = vnb[i2];
    float4 o;
    o.x = a.x + bb.x + cc.x;
    o.y = a.y + bb.y + cc.y;
    o.z = a.z + bb.z + cc.z;
    o.w = 0.f;
    fas4[i] = o;
}

// ---------------------------------------------------------------------------
// D4 (k_pixel): proven round-4 code. STRIDED 8 px/thread: coalesced input
// loads (256B/wave) and output stores (1KB/wave); 8 independent clamped
// gathers in flight per thread.
// ---------------------------------------------------------------------------
__device__ __forceinline__ nf4 pixel_one(int f, float d, float4 p) {
    float m = (f >= 0) ? 1.0f : 0.0f;
    float px = p.x * m, py = p.y * m, pz = p.z * m;
    float prob = m / (1.0f + __expf(d * 1.0e4f));  // sigmoid(-d/SIGMA) * mask
    float n2 = px * px + py * py + pz * pz;
    float inv = 1.0f / fmaxf(sqrtf(n2), 1e-12f);
    float hitadd = (n2 > 0.f) ? 0.f : 1.0f;
    nf4 o;
    o.x = px * inv + hitadd;
    o.y = py * inv + hitadd;
    o.z = pz * inv + hitadd;
    o.w = 1.0f - prob;
    return o;
}

#define PPT 8
#define PIX_BLOCK (256 * PPT)  // 2048 pixels/block; 2048 blocks; 128 blocks/batch

__global__ __launch_bounds__(256) void k_pixel(const int* __restrict__ p2f,
                                               const float* __restrict__ dists,
                                               const float4* __restrict__ fas4,
                                               nf4* __restrict__ out) {
    int base = blockIdx.x * PIX_BLOCK;
    int t = threadIdx.x;
    int b = base >> 18;  // H*W = 2^18; a 2048-pixel block never crosses a batch
    const float4* fasb = fas4 + (size_t)b * NFF;

    int   f[PPT];
    float d[PPT];
    float4 p[PPT];

#pragma unroll
    for (int k = 0; k < PPT; k++)
        f[k] = __builtin_nontemporal_load(p2f + base + k * 256 + t);
#pragma unroll
    for (int k = 0; k < PPT; k++)
        d[k] = __builtin_nontemporal_load(dists + base + k * 256 + t);

#pragma unroll
    for (int k = 0; k < PPT; k++)
        p[k] = fasb[min(max(f[k], 0), NFF - 1)];

#pragma unroll
    for (int k = 0; k < PPT; k++) {
        nf4 o = pixel_one(f[k], d[k], p[k]);
        __builtin_nontemporal_store(o, out + base + k * 256 + t);
    }
}

// ---------------------------------------------------------------------------
// Fallback path (proven round-4 pipeline, 159.7us) if workspace is too small
// for the 21MB partial buffer.
// ---------------------------------------------------------------------------
__global__ __launch_bounds__(256) void k_fn_adj(const float* __restrict__ verts,
                                                const int* __restrict__ faces,
                                                float4* __restrict__ fn4,
                                                int* __restrict__ cursor,
                                                int* __restrict__ adj) {
    if (blockIdx.x < 861) {
        int i = blockIdx.x * 256 + threadIdx.x;
        int b = i / NFF;
        int f = i - b * NFF;
        int i0 = faces[3 * f + 0];
        int i1 = faces[3 * f + 1];
        int i2 = faces[3 * f + 2];
        const float* vb = verts + (size_t)b * (VV * 3);
        float ax = vb[3 * i0 + 0], ay = vb[3 * i0 + 1], az = vb[3 * i0 + 2];
        float bx = vb[3 * i1 + 0], by = vb[3 * i1 + 1], bz = vb[3 * i1 + 2];
        float cx = vb[3 * i2 + 0], cy = vb[3 * i2 + 1], cz = vb[3 * i2 + 2];
        float e1x = bx - ax, e1y = by - ay, e1z = bz - az;
        float e2x = cx - ax, e2y = cy - ay, e2z = cz - az;
        float4 n;
        n.x = e1y * e2z - e1z * e2y;
        n.y = e1z * e2x - e1x * e2z;
        n.z = e1x * e2y - e1y * e2x;
        n.w = 0.f;
        fn4[i] = n;
    } else {
        int f = (blockIdx.x - 861) * 256 + threadIdx.x;
        if (f < NFF) {
            int i0 = faces[3 * f + 0];
            int i1 = faces[3 * f + 1];
            int i2 = faces[3 * f + 2];
            int s0 = atomicAdd(&cursor[i0], 1);
            if (s0 < CAP) adj[s0 * VV + i0] = f;
            int s1 = atomicAdd(&cursor[i1], 1);
            if (s1 < CAP) adj[s1 * VV + i1] = f;
            int s2 = atomicAdd(&cursor[i2], 1);
            if (s2 < CAP) adj[s2 * VV + i2] = f;
        }
    }
}

__global__ __launch_bounds__(256) void k_vn(const float4* __restrict__ fn4,
                                            const int* __restrict__ cursor,
                                            const int* __restrict__ adj,
                                            float4* __restrict__ vn4) {
    int i = blockIdx.x * 256 + threadIdx.x;
    if (i >= BB * VV) return;
    int b = i / VV;
    int v = i - b * VV;
    int deg = min(cursor[v], CAP);
    float x = 0.f, y = 0.f, z = 0.f;
    const float4* fnb = fn4 + (size_t)b * NFF;
    for (int j = 0; j < deg; j++) {
        float4 n = fnb[adj[j * VV + v]];
        x += n.x; y += n.y; z += n.z;
    }
    float inv = 1.0f / fmaxf(sqrtf(x * x + y * y + z * z), 1e-6f);
    float4 o; o.x = x * inv; o.y = y * inv; o.z = z * inv; o.w = 0.f;
    vn4[i] = o;
}

// ---------------------------------------------------------------------------
extern "C" void kernel_launch(void* const* d_in, const int* in_sizes, int n_in,
                              void* d_out, int out_size, void* d_ws, size_t ws_size,
                              hipStream_t stream) {
    const float* verts = (const float*)d_in[0];
    // d_in[1] = zbuf: dead in the reference's returned value -> never read
    const float* dists = (const float*)d_in[2];
    const int* faces   = (const int*)d_in[3];
    const int* p2f     = (const int*)d_in[4];

    const size_t partial_bytes = (size_t)BB * NS * 3 * VV * sizeof(float);  // 21.2 MB
    const size_t vn_bytes      = (size_t)BB * VV * 16;                      // 1.76 MB
    const size_t fas_bytes     = (size_t)BB * NFF * 16;                     // 3.53 MB

    int nbv = BB * VV;   // 110240

    if (ws_size >= partial_bytes + vn_bytes + fas_bytes) {
        // --- primary path: segmented scatter-reduce, 4 dispatches, no CSR ---
        char* w = (char*)d_ws;
        float* partial = (float*)w;  w += partial_bytes;
        float4* vn4    = (float4*)w; w += vn_bytes;
        float4* fas4   = (float4*)w;

        k_scatter<<<BB * NS, 512, 0, stream>>>(verts, faces, partial);
        k_vred<<<(nbv + 255) / 256, 256, 0, stream>>>(partial, vn4);
        k_fas<<<861, 256, 0, stream>>>(vn4, faces, fas4);
        k_pixel<<<BB * HH * WW / PIX_BLOCK, 256, 0, stream>>>(p2f, dists, fas4, (nf4*)d_out);
    } else {
        // --- fallback: proven round-4 CSR pipeline ---
        char* w = (char*)d_ws;
        float4* fn4  = (float4*)w;  w += (size_t)BB * NFF * 16;
        float4* vn4  = (float4*)w;  w += vn_bytes;
        float4* fas4 = (float4*)w;  w += fas_bytes;
        int* cursor  = (int*)w;     w += (VV * 4 + 15) / 16 * 16;
        int* adj     = (int*)w;

        (void)hipMemsetAsync(cursor, 0, VV * sizeof(int), stream);
        k_fn_adj<<<861 + (NFF + 255) / 256, 256, 0, stream>>>(verts, faces, fn4, cursor, adj);
        k_vn<<<(nbv + 255) / 256, 256, 0, stream>>>(fn4, cursor, adj, vn4);
        k_fas<<<861, 256, 0, stream>>>(vn4, faces, fas4);
        k_pixel<<<BB * HH * WW / PIX_BLOCK, 256, 0, stream>>>(p2f, dists, fas4, (nf4*)d_out);
    }
}